// Round 6
// baseline (252.218 us; speedup 1.0000x reference)
//
#include <hip/hip_runtime.h>
#include <hip/hip_bf16.h>

#define N_NODES 50000
#define N_EDGES 800000
#define IN_FEAT 512
#define HF 256          // HEADS * OUT_FEAT
#define BM 64
#define BN 256
#define BK 64
#define LDT 72          // padded LDS leading dim (elements)
#define SCAN_BLK 1024
#define NSCAN 49        // ceil(50000/1024)
#define GEMM_BLOCKS 782 // ceil(50000/64)
#define CNT_BLOCKS 218

typedef short short8 __attribute__((ext_vector_type(8)));
typedef unsigned short ushort8 __attribute__((ext_vector_type(8)));
typedef float f32x4 __attribute__((ext_vector_type(4)));

__device__ __forceinline__ unsigned short f2bf(float f) {
    union { float f; unsigned u; } c{f};
    unsigned r = c.u + 0x7FFFu + ((c.u >> 16) & 1u);   // RNE
    return (unsigned short)(r >> 16);
}
__device__ __forceinline__ float bf2f(unsigned short b) {
    union { unsigned u; float f; } c;
    c.u = ((unsigned)b) << 16;
    return c.f;
}
__device__ __forceinline__ short8 pack8(const float4& a, const float4& b) {
    short8 v;
    v[0] = (short)f2bf(a.x); v[1] = (short)f2bf(a.y);
    v[2] = (short)f2bf(a.z); v[3] = (short)f2bf(a.w);
    v[4] = (short)f2bf(b.x); v[5] = (short)f2bf(b.y);
    v[6] = (short)f2bf(b.z); v[7] = (short)f2bf(b.w);
    return v;
}

// blocks [0,782): h = x @ W^T (bf16 MFMA).  blocks [782,1000): in-degree count.
__global__ __launch_bounds__(512, 6) void gemm_count_kernel(const float* __restrict__ X,
                                                            const float* __restrict__ Wm,
                                                            unsigned short* __restrict__ H,
                                                            const int* __restrict__ ei,
                                                            int* __restrict__ cursor) {
    if (blockIdx.x >= GEMM_BLOCKS) {
        // ---- count blocks: run concurrently with gemm blocks ----
        const int cb = blockIdx.x - GEMM_BLOCKS;
        const int stride = CNT_BLOCKS * 512;
        for (int e = cb * 512 + threadIdx.x; e < N_EDGES; e += stride)
            atomicAdd(&cursor[ei[N_EDGES + e]], 1);
        return;
    }

    __shared__ short As[BM * LDT];   //  9.2 KB
    __shared__ short Bs[BN * LDT];   // 36.9 KB  -> 46 KB total, 3 blocks/CU

    const int t    = threadIdx.x;
    const int lane = t & 63;
    const int w    = t >> 6;        // wave 0..7
    const int wr   = w >> 2;        // 0..1 (32 rows each)
    const int wc   = w & 3;         // 0..3 (64 cols each)
    const int brow = blockIdx.x * BM;

    const int tr = t >> 3;          // 0..63: row per staging round
    const int tc = (t & 7) * 8;     // col start (8 floats)

    int arow = brow + tr;
    if (arow >= N_NODES) arow = N_NODES - 1;

    f32x4 acc[2][4] = {};

    for (int kt = 0; kt < IN_FEAT; kt += BK) {
        // stage A: 64 rows x 64 cols, 1 round
        {
            const float* ga = X + (size_t)arow * IN_FEAT + kt + tc;
            const float4 a0 = *(const float4*)(ga);
            const float4 a1 = *(const float4*)(ga + 4);
            *(short8*)(&As[tr * LDT + tc]) = pack8(a0, a1);
        }
        // stage B: 256 rows x 64 cols, 4 rounds
#pragma unroll
        for (int r = 0; r < 4; ++r) {
            const float* gb = Wm + (size_t)(r * 64 + tr) * IN_FEAT + kt + tc;
            const float4 b0 = *(const float4*)(gb);
            const float4 b1 = *(const float4*)(gb + 4);
            *(short8*)(&Bs[(r * 64 + tr) * LDT + tc]) = pack8(b0, b1);
        }
        __syncthreads();

#pragma unroll
        for (int ks = 0; ks < 2; ++ks) {
            const int koff = ks * 32 + (lane >> 4) * 8;
            short8 a[2], b[4];
#pragma unroll
            for (int m = 0; m < 2; ++m)
                a[m] = *(const short8*)(&As[(wr * 32 + m * 16 + (lane & 15)) * LDT + koff]);
#pragma unroll
            for (int n = 0; n < 4; ++n)
                b[n] = *(const short8*)(&Bs[(wc * 64 + n * 16 + (lane & 15)) * LDT + koff]);
#pragma unroll
            for (int m = 0; m < 2; ++m)
#pragma unroll
                for (int n = 0; n < 4; ++n)
                    acc[m][n] = __builtin_amdgcn_mfma_f32_16x16x32_bf16(a[m], b[n], acc[m][n], 0, 0, 0);
        }
        __syncthreads();
    }

#pragma unroll
    for (int m = 0; m < 2; ++m) {
        const int row0 = brow + wr * 32 + m * 16 + (lane >> 4) * 4;
#pragma unroll
        for (int n = 0; n < 4; ++n) {
            const int col = wc * 64 + n * 16 + (lane & 15);
#pragma unroll
            for (int j = 0; j < 4; ++j) {
                const int row = row0 + j;
                if (row < N_NODES) H[(size_t)row * HF + col] = f2bf(acc[m][n][j]);
            }
        }
    }
}

// phase A: per-block (1024 items) local exclusive scan + block total
__global__ __launch_bounds__(256) void scanA_kernel(const int* __restrict__ counts,
                                                    int* __restrict__ offs,
                                                    int* __restrict__ bsum) {
    __shared__ int wtot[4];
    const int t = threadIdx.x;
    const int lane = t & 63, wv = t >> 6;
    const int base = blockIdx.x * SCAN_BLK + t * 4;
    int4 c = {0, 0, 0, 0};
    if (base + 3 < N_NODES) c = *(const int4*)(counts + base);
    else {
        if (base + 0 < N_NODES) c.x = counts[base + 0];
        if (base + 1 < N_NODES) c.y = counts[base + 1];
        if (base + 2 < N_NODES) c.z = counts[base + 2];
        if (base + 3 < N_NODES) c.w = counts[base + 3];
    }
    const int tsum = c.x + c.y + c.z + c.w;
    int s = tsum;
#pragma unroll
    for (int d = 1; d < 64; d <<= 1) {
        const int u = __shfl_up(s, d, 64);
        if (lane >= d) s += u;
    }
    if (lane == 63) wtot[wv] = s;
    __syncthreads();
    int wpre = 0;
    for (int i = 0; i < wv; ++i) wpre += wtot[i];
    const int e0 = wpre + s - tsum;
    if (base + 0 < N_NODES) offs[base + 0] = e0;
    if (base + 1 < N_NODES) offs[base + 1] = e0 + c.x;
    if (base + 2 < N_NODES) offs[base + 2] = e0 + c.x + c.y;
    if (base + 3 < N_NODES) offs[base + 3] = e0 + c.x + c.y + c.z;
    if (t == 255) bsum[blockIdx.x] = wpre + s;   // block total
}

// phase C: each block re-scans the 49 totals itself, adds base, emits offs+cursor
__global__ __launch_bounds__(256) void scanC_kernel(int* __restrict__ offs,
                                                    const int* __restrict__ bsum,
                                                    int* __restrict__ cursor) {
    __shared__ int pre[NSCAN];
    const int t = threadIdx.x;
    if (t < 64) {
        const int v = (t < NSCAN) ? bsum[t] : 0;
        int s = v;
#pragma unroll
        for (int d = 1; d < 64; d <<= 1) {
            const int u = __shfl_up(s, d, 64);
            if (t >= d) s += u;
        }
        if (t < NSCAN) pre[t] = s - v;   // exclusive
    }
    __syncthreads();
    const int base = blockIdx.x * SCAN_BLK + t * 4;
    if (blockIdx.x == 0 && t == 0) offs[N_NODES] = N_EDGES;
    if (base >= N_NODES) return;
    const int add = pre[blockIdx.x];
    if (base + 3 < N_NODES) {
        int4 v = *(const int4*)(offs + base);
        v.x += add; v.y += add; v.z += add; v.w += add;
        *(int4*)(offs + base) = v;
        *(int4*)(cursor + base) = v;
    } else {
        for (int k = 0; k < 4 && base + k < N_NODES; ++k) {
            const int v = offs[base + k] + add;
            offs[base + k] = v;
            cursor[base + k] = v;
        }
    }
}

// bucket[pos] = src, pos = cursor[dst]++
__global__ __launch_bounds__(256) void fill_kernel(const int* __restrict__ ei,
                                                   int* __restrict__ cursor,
                                                   int* __restrict__ bucket) {
    const int e = blockIdx.x * blockDim.x + threadIdx.x;
    if (e >= N_EDGES) return;
    const int src = ei[e];
    const int dst = ei[N_EDGES + e];
    const int pos = atomicAdd(&cursor[dst], 1);
    bucket[pos] = src;
}

// one wave per node; quarter-wave (16 lanes) per edge, 4 edges in flight.
// lane = 16*q + j: quarter q walks edges beg+q, beg+q+4, ...; lane j reads
// 32 B (cols [16j,16j+16)) of each gathered row.
__global__ __launch_bounds__(256) void aggregate_kernel(const unsigned short* __restrict__ h,
                                                        const int* __restrict__ offs,
                                                        const int* __restrict__ bucket,
                                                        float* __restrict__ out) {
    const int node = (int)(((size_t)blockIdx.x * blockDim.x + threadIdx.x) >> 6);
    const int lane = threadIdx.x & 63;
    if (node >= N_NODES) return;
    const int q = lane >> 4;
    const int j = lane & 15;
    const int beg = offs[node];
    const int end = offs[node + 1];
    const int c = end - beg;

    float acc[16];
#pragma unroll
    for (int k = 0; k < 16; ++k) acc[k] = 0.f;

    for (int i = beg + q; i < end; i += 4) {
        const int src = bucket[i];
        const ushort8* p = (const ushort8*)(h + (size_t)src * HF + j * 16);
        const ushort8 v0 = p[0];
        const ushort8 v1 = p[1];
#pragma unroll
        for (int k = 0; k < 8; ++k) acc[k]     += bf2f((unsigned short)v0[k]);
#pragma unroll
        for (int k = 0; k < 8; ++k) acc[8 + k] += bf2f((unsigned short)v1[k]);
    }
    // reduce across the 4 quarters (lanes with equal j end up identical)
#pragma unroll
    for (int k = 0; k < 16; ++k) {
        acc[k] += __shfl_xor(acc[k], 16, 64);
        acc[k] += __shfl_xor(acc[k], 32, 64);
    }

    // lane (q,j) writes cols [16j + 4q, 16j + 4q + 4)  — static indices only
    float a0, a1, a2, a3;
    if (q == 0)      { a0 = acc[0];  a1 = acc[1];  a2 = acc[2];  a3 = acc[3];  }
    else if (q == 1) { a0 = acc[4];  a1 = acc[5];  a2 = acc[6];  a3 = acc[7];  }
    else if (q == 2) { a0 = acc[8];  a1 = acc[9];  a2 = acc[10]; a3 = acc[11]; }
    else             { a0 = acc[12]; a1 = acc[13]; a2 = acc[14]; a3 = acc[15]; }

    float4 r;
    if (c > 0) {
        const float inv = 1.0f / (float)c;
        r.x = a0 * inv; r.y = a1 * inv; r.z = a2 * inv; r.w = a3 * inv;
    } else {
        const ushort8 v = *(const ushort8*)(h + (size_t)node * HF + j * 16 + (q >> 1) * 8);
        const int b = (q & 1) * 4;
        r.x = bf2f((unsigned short)v[b + 0]);
        r.y = bf2f((unsigned short)v[b + 1]);
        r.z = bf2f((unsigned short)v[b + 2]);
        r.w = bf2f((unsigned short)v[b + 3]);
    }
    *(float4*)(out + (size_t)node * HF + j * 16 + q * 4) = r;
}

extern "C" void kernel_launch(void* const* d_in, const int* in_sizes, int n_in,
                              void* d_out, int out_size, void* d_ws, size_t ws_size,
                              hipStream_t stream) {
    const float* x = (const float*)d_in[0];
    const float* W = (const float*)d_in[1];
    const int* ei  = (const int*)d_in[2];
    float* out = (float*)d_out;

    char* ws = (char*)d_ws;
    unsigned short* h = (unsigned short*)ws;                    // 25.6 MB
    int* bucket = (int*)(ws + (size_t)N_NODES * HF * 2);        // 3.2 MB
    int* offs   = (int*)((char*)bucket + (size_t)N_EDGES * 4);  // 200 KB (+1)
    int* cursor = (int*)((char*)offs + (size_t)(N_NODES + 4) * 4);
    int* bsum   = (int*)((char*)cursor + (size_t)(N_NODES + 4) * 4);

    hipMemsetAsync(cursor, 0, (size_t)N_NODES * sizeof(int), stream);

    gemm_count_kernel<<<GEMM_BLOCKS + CNT_BLOCKS, 512, 0, stream>>>(x, W, h, ei, cursor);

    scanA_kernel<<<NSCAN, 256, 0, stream>>>(cursor, offs, bsum);
    scanC_kernel<<<NSCAN, 256, 0, stream>>>(offs, bsum, cursor);

    const int eblocks = (N_EDGES + 255) / 256;
    fill_kernel<<<eblocks, 256, 0, stream>>>(ei, cursor, bucket);

    aggregate_kernel<<<(N_NODES * 64 + 255) / 256, 256, 0, stream>>>(h, offs, bucket, out);
}